// Round 6
// baseline (125.053 us; speedup 1.0000x reference)
//
#include <hip/hip_runtime.h>

// CostConcatenation: out[b,d,h,w, 0:16] = left[b,h,w,:]        (if valid else 0)
//                    out[b,d,h,w,16:32] = right[b,h,w-disp,:]  (if valid else 0)
// disp = d - 112 ; idx = w + (112 - d) ; valid = 0<=idx<W
// Output (B, D, H, W, 2C) fp32 = 604 MB -> write-BW bound. Fill comparator 6.76 TB/s.
// R3: builtin nt stores -> 118 us. R5: sc0/sc1 system-scope stores BREAK harness
// coherence (nan) -> plain nt only.
// R6: XCD-locality swizzle. Default round-robin makes every XCD stream all
// 4.7 MB of inputs through its 4 MB L2 while 75 MB/XCD of writes evict them ->
// repeated HBM re-reads. Remap: XCD k owns h-stripe [12k,12k+12) for all (d,b):
//   p = blockIdx.x; xcd = p&7; i = p>>3; b = i/1536; r = i%1536;
//   d = r/12; h = xcd*12 + r%12
// Per-XCD input footprint 576 KB (L2-resident); writes = 288 KB sequential runs.

constexpr int B_ = 2;
constexpr int H_ = 96;
constexpr int W_ = 192;
constexpr int D_ = 128;

typedef float v4f __attribute__((ext_vector_type(4)));

__global__ __launch_bounds__(256) void cost_concat_kernel(
    const v4f* __restrict__ left,
    const v4f* __restrict__ right,
    v4f* __restrict__ out)
{
    // XCD-aware decode (all uniform scalar math, consts -> magic-mul)
    const unsigned p   = blockIdx.x;          // [0, 24576)
    const unsigned xcd = p & 7u;
    const unsigned i   = p >> 3;              // [0, 3072)
    const unsigned b   = i / 1536u;           // {0,1}
    const unsigned r   = i - b * 1536u;       // [0, 1536) = 128 d * 12 h
    const unsigned d   = r / 12u;             // [0, 128)
    const unsigned h   = xcd * 12u + (r - d * 12u);  // [0, 96)

    const int rowBase = (b * H_ + h) * (W_ * 4);            // float4 units
    const long long outBase =
        (((long long)(b * D_ + d)) * H_ + h) * (long long)(W_ * 8);

    const int shift = 112 - (int)d;  // idx = w + shift

    const v4f* __restrict__ lrow = left  + rowBase;
    const v4f* __restrict__ rrow = right + rowBase;
    v4f* __restrict__ orow = out + outBase;

    // W*8 = 1536 float4 per row, 256 threads -> 6 fully-unrolled iterations
    #pragma unroll
    for (int j = threadIdx.x; j < W_ * 8; j += 256) {
        const int w  = j >> 3;   // cell within row
        const int c4 = j & 7;    // which float4 within the 32-float cell
        const int idx = w + shift;

        v4f v = (v4f)(0.f);
        if ((unsigned)idx < (unsigned)W_) {
            const v4f* src = (c4 < 4)
                ? (lrow + w   * 4 + c4)
                : (rrow + idx * 4 + (c4 - 4));
            v = *src;
        }
        __builtin_nontemporal_store(v, orow + j);
    }
}

extern "C" void kernel_launch(void* const* d_in, const int* in_sizes, int n_in,
                              void* d_out, int out_size, void* d_ws, size_t ws_size,
                              hipStream_t stream)
{
    const v4f* left  = (const v4f*)d_in[0];
    const v4f* right = (const v4f*)d_in[1];
    v4f* out = (v4f*)d_out;

    // 24576 blocks; bijective XCD decode inside the kernel
    cost_concat_kernel<<<dim3(B_ * D_ * H_), 256, 0, stream>>>(left, right, out);
}

// Round 7
// 115.942 us; speedup vs baseline: 1.0786x; 1.0786x over previous
//
#include <hip/hip_runtime.h>

// CostConcatenation: out[b,d,h,w, 0:16] = left[b,h,w,:]        (if valid else 0)
//                    out[b,d,h,w,16:32] = right[b,h,w-disp,:]  (if valid else 0)
// disp = d - 112 ; idx = w + (112 - d) ; valid = 0<=idx<W
// Output (B, D, H, W, 2C) fp32 = 604 MB -> write-BW bound.
// History: R1 plain stores 129us. R3 nt stores 118us. R4 d-tile (reads) neutral.
// R5 sc0/sc1 stores break harness coherence (nan). R6 XCD h-stripe swizzle -6%.
// => reads are cache-served and irrelevant; output sweep structure is what's left.
// R7: mimic the 6.76 TB/s fill kernel's structure exactly: 2048 persistent
// blocks (8/CU, full 32-wave occupancy), linear grid-stride sweep of the flat
// output (one monotone 8 MB sliding window -> best DRAM page sequentiality,
// no 24k-block dispatch generations). Decode (b,d,h,w,c4) per iteration with
// magic-mul divisions (VALUBusy was 5% -> headroom).

constexpr int B_ = 2;
constexpr int H_ = 96;
constexpr int W_ = 192;
constexpr int D_ = 128;

typedef float v4f __attribute__((ext_vector_type(4)));

constexpr unsigned TOTAL4   = 37748736u;      // B*D*H*W*8 float4 elements (604 MB)
constexpr unsigned NBLK     = 2048u;          // 8 blocks/CU * 256 CU
constexpr unsigned NTHREADS = NBLK * 256u;    // 524288
constexpr int      ITERS    = TOTAL4 / NTHREADS;  // 72 exactly

__global__ __launch_bounds__(256) void cost_concat_kernel(
    const v4f* __restrict__ left,
    const v4f* __restrict__ right,
    v4f* __restrict__ out)
{
    unsigned j = blockIdx.x * 256u + threadIdx.x;

    #pragma unroll 4
    for (int it = 0; it < ITERS; ++it, j += NTHREADS) {
        // decode flat float4 index -> (rowid, w, c4); rowid = (b*128+d)*96+h
        const unsigned rowid = j / 1536u;            // magic mul
        const unsigned rr    = j - rowid * 1536u;
        const unsigned w     = rr >> 3;
        const unsigned c4    = rr & 7u;
        const unsigned b     = rowid / 12288u;       // 128*96
        const unsigned t     = rowid - b * 12288u;
        const unsigned d     = t / 96u;              // magic mul
        const unsigned h     = t - d * 96u;

        const int idx = (int)w + 112 - (int)d;       // right-image column
        const unsigned rowBase = (b * H_ + h) * (W_ * 4);  // input row, float4 units

        v4f v = (v4f)(0.f);
        if ((unsigned)idx < (unsigned)W_) {
            const v4f* src = (c4 < 4u)
                ? (left  + rowBase + w * 4u + c4)
                : (right + rowBase + (unsigned)idx * 4u + (c4 - 4u));
            v = *src;
        }
        __builtin_nontemporal_store(v, out + j);
    }
}

extern "C" void kernel_launch(void* const* d_in, const int* in_sizes, int n_in,
                              void* d_out, int out_size, void* d_ws, size_t ws_size,
                              hipStream_t stream)
{
    const v4f* left  = (const v4f*)d_in[0];
    const v4f* right = (const v4f*)d_in[1];
    v4f* out = (v4f*)d_out;

    cost_concat_kernel<<<dim3(NBLK), 256, 0, stream>>>(left, right, out);
}